// Round 7
// baseline (317.247 us; speedup 1.0000x reference)
//
#include <hip/hip_runtime.h>
#include <math.h>

#define FIN 128
#define D1  256
#define D2  128
#define KCL 32
#define CAP 8192          // max edges per 256-node bin (avg ~4082, huge headroom)

typedef __attribute__((ext_vector_type(8))) short short8;
typedef __attribute__((ext_vector_type(4))) float floatx4;

__device__ __forceinline__ ushort f2bf(float f) {
    unsigned u = __float_as_uint(f);
    unsigned r = (u + 0x7fffu + ((u >> 16) & 1u)) >> 16;
    return (ushort)r;
}
__device__ __forceinline__ float bf2f(ushort h) {
    return __uint_as_float(((unsigned)h) << 16);
}

// ---------------- P1: bin-scatter edges, BOTH directions in one edge read ----------------
__global__ __launch_bounds__(256) void k_p1(const int* __restrict__ edges, int E, int NBIN,
                                            int* __restrict__ gcnt, unsigned* __restrict__ binbuf) {
    __shared__ int h[512], base[512], cur[512];
    int t = threadIdx.x;
    h[t] = 0; h[t + 256] = 0;
    __syncthreads();
    int chunk = (E + gridDim.x - 1) / gridDim.x;
    int lo = blockIdx.x * chunk, hi = min(lo + chunk, E);
    for (int e = lo + t; e < hi; e += 256) {
        int r = edges[e], c = edges[E + e];
        atomicAdd(&h[c >> 8], 1);
        atomicAdd(&h[256 + (r >> 8)], 1);
    }
    __syncthreads();
    if (t < NBIN) {
        base[t]       = atomicAdd(&gcnt[t],        h[t]);
        base[256 + t] = atomicAdd(&gcnt[NBIN + t], h[256 + t]);
    }
    cur[t] = 0; cur[t + 256] = 0;
    __syncthreads();
    for (int e = lo + t; e < hi; e += 256) {
        int r = edges[e], c = edges[E + e];
        int b0 = c >> 8;                              // dir0: key dst, store src
        int p0 = base[b0] + atomicAdd(&cur[b0], 1);
        if (p0 < CAP) binbuf[(size_t)b0 * CAP + p0] = (unsigned)r | ((unsigned)(c & 255) << 16);
        int b1 = r >> 8;                              // dir1: key src, store dst
        int p1 = base[256 + b1] + atomicAdd(&cur[256 + b1], 1);
        if (p1 < CAP) binbuf[((size_t)NBIN + b1) * CAP + p1] = (unsigned)c | ((unsigned)(r & 255) << 16);
    }
}

// ---------------- P2: per-bin CSR build + degrees + dinv ----------------
__global__ __launch_bounds__(256) void k_p2(const unsigned* __restrict__ binbuf, const int* __restrict__ gcnt,
                                            int N, int E, int NBIN,
                                            int* __restrict__ col_ptr, int* __restrict__ row_ptr,
                                            ushort* __restrict__ col_idx, ushort* __restrict__ row_idx,
                                            float* __restrict__ dinv1, float* __restrict__ dinv2) {
    int d = blockIdx.y, b = blockIdx.x, t = threadIdx.x;
    __shared__ int sc[256], h[256], hx[256], cur[256];
    sc[t] = (t < NBIN) ? gcnt[d * NBIN + t] : 0;
    __syncthreads();
    for (int st = 1; st < 256; st <<= 1) {
        int u = (t >= st) ? sc[t - st] : 0;
        __syncthreads();
        sc[t] += u;
        __syncthreads();
    }
    int cnt_b = gcnt[d * NBIN + b];
    int binbase = sc[b] - cnt_b;
    h[t] = 0;
    __syncthreads();
    const unsigned* bb = binbuf + ((size_t)d * NBIN + b) * CAP;
    int m = min(cnt_b, CAP);
    for (int i = t; i < m; i += 256) atomicAdd(&h[bb[i] >> 16], 1);
    __syncthreads();
    int hv = h[t];
    hx[t] = hv;
    __syncthreads();
    for (int st = 1; st < 256; st <<= 1) {
        int u = (t >= st) ? hx[t - st] : 0;
        __syncthreads();
        hx[t] += u;
        __syncthreads();
    }
    int excl = hx[t] - hv;
    int node = b * 256 + t;
    if (node < N) {
        if (d == 0) {
            dinv1[node] = rsqrtf((float)hv + 1.0f);
            col_ptr[node] = binbase + excl;
            if (node == N - 1) col_ptr[N] = E;
        } else {
            dinv2[node] = hv ? rsqrtf((float)hv) : 0.0f;
            row_ptr[node] = binbase + excl;
            if (node == N - 1) row_ptr[N] = E;
        }
    }
    hx[t] = excl;
    cur[t] = 0;
    __syncthreads();
    ushort* oidx = d ? row_idx : col_idx;
    for (int i = t; i < m; i += 256) {
        unsigned p = bb[i];
        int nl = p >> 16;
        int rk = atomicAdd(&cur[nl], 1);
        oidx[binbase + hx[nl] + rk] = (ushort)(p & 0xffff);
    }
}

// ---------------- v_j = dinv1[j]*(dinv1[j] + sum_{i in out(j)} dinv1[i]) ----------------
__global__ void k_v(const int* __restrict__ row_ptr, const ushort* __restrict__ row_idx,
                    const float* __restrict__ dinv1, float* __restrict__ v, int N) {
    int j = blockIdx.x * blockDim.x + threadIdx.x;
    if (j >= N) return;
    int lo = row_ptr[j], hi = row_ptr[j + 1];
    float s0 = dinv1[j], s1 = 0.f, s2 = 0.f, s3 = 0.f;
    int e = lo;
    for (; e + 4 <= hi; e += 4) {
        int i0 = row_idx[e], i1 = row_idx[e + 1], i2 = row_idx[e + 2], i3 = row_idx[e + 3];
        s0 += dinv1[i0]; s1 += dinv1[i1]; s2 += dinv1[i2]; s3 += dinv1[i3];
    }
    for (; e < hi; e++) s0 += dinv1[row_idx[e]];
    v[j] = dinv1[j] * ((s0 + s1) + (s2 + s3));
}

// ---------------- fused: Xs = bf16(dinv1*X), xsum[c] += v[j]*X[j][c] ----------------
__global__ __launch_bounds__(256) void k_prep(const float* __restrict__ X, const float* __restrict__ dinv1,
                                              const float* __restrict__ vvec,
                                              unsigned* __restrict__ Xs2, float* __restrict__ xsum, int N) {
    int t = threadIdx.x;
    int cp = t & 63;        // col-pair (cols 2cp, 2cp+1)
    int rg = t >> 6;        // row group 0..3
    float s0 = 0.f, s1 = 0.f;
    for (int j0 = blockIdx.x * 4; j0 < N; j0 += gridDim.x * 4) {
        int j = j0 + rg;
        if (j < N) {
            float2 x = ((const float2*)X)[(long)j * 64 + cp];
            float d = dinv1[j];
            Xs2[(long)j * 64 + cp] = (unsigned)f2bf(d * x.x) | ((unsigned)f2bf(d * x.y) << 16);
            float v = vvec[j];
            s0 += v * x.x;
            s1 += v * x.y;
        }
    }
    __shared__ float red[256][2];
    red[t][0] = s0; red[t][1] = s1;
    __syncthreads();
    if (rg == 0) {
        float r0 = red[cp][0] + red[64 + cp][0] + red[128 + cp][0] + red[192 + cp][0];
        float r1 = red[cp][1] + red[64 + cp][1] + red[128 + cp][1] + red[192 + cp][1];
        atomicAdd(&xsum[2 * cp], r0);
        atomicAdd(&xsum[2 * cp + 1], r1);
    }
}

// ---------------- Wc = W1 @ fc1_W (fp32) -> bf16 transposed; bc; fc2_W -> bf16 transposed ----------------
__global__ __launch_bounds__(128) void k_wc(const float* __restrict__ W1, const float* __restrict__ fc1W,
                                            const float* __restrict__ b1, const float* __restrict__ fc1b,
                                            const float* __restrict__ fc2W,
                                            ushort* __restrict__ Wct, float* __restrict__ bc,
                                            ushort* __restrict__ fc2Wt) {
    int t = threadIdx.x;
    if (blockIdx.x == D2) {   // extra block: transpose fc2_W [128][32] -> [32][128] bf16
        for (int idx = t; idx < D2 * KCL; idx += 128) {
            int k = idx >> 5, n = idx & 31;
            fc2Wt[n * D2 + k] = f2bf(fc2W[idx]);
        }
        return;
    }
    int n = blockIdx.x, k = t;
    __shared__ float fcol[256];
    fcol[k] = fc1W[k * 128 + n];
    fcol[k + 128] = fc1W[(k + 128) * 128 + n];
    __syncthreads();
    float acc = 0.f;
    for (int m = 0; m < 256; m++) acc += W1[k * 256 + m] * fcol[m];
    Wct[n * 128 + k] = f2bf(acc);
    if (k == 0) {
        float a = fc1b[n];
        for (int m = 0; m < 256; m++) a += b1[m] * fcol[m];
        bc[n] = a;
    }
}

// ---------------- aggX[i] = bf16( dinv1[i] * sum_{j in in(i)+self} Xs[j] ) ----------------
__global__ __launch_bounds__(256) void k_aggX(const unsigned* __restrict__ Xs2,
                                              const int* __restrict__ col_ptr, const ushort* __restrict__ col_idx,
                                              const float* __restrict__ dinv1,
                                              unsigned* __restrict__ aggX2, int N) {
    int wv = threadIdx.x >> 6, l = threadIdx.x & 63;
    int i = blockIdx.x * 4 + wv;
    if (i >= N) return;
    int lo = col_ptr[i], hi = col_ptr[i + 1];
    unsigned p0 = Xs2[(long)i * 64 + l];
    float a0 = bf2f((ushort)(p0 & 0xffff));
    float a1 = bf2f((ushort)(p0 >> 16));
    float b0 = 0.f, b1v = 0.f, c0 = 0.f, c1 = 0.f, d0 = 0.f, d1 = 0.f;
    int e = lo;
    for (; e + 8 <= hi; e += 8) {
        int s0 = col_idx[e + 0], s1 = col_idx[e + 1], s2 = col_idx[e + 2], s3 = col_idx[e + 3];
        int s4 = col_idx[e + 4], s5 = col_idx[e + 5], s6 = col_idx[e + 6], s7 = col_idx[e + 7];
        unsigned q0 = Xs2[(long)s0 * 64 + l];
        unsigned q1 = Xs2[(long)s1 * 64 + l];
        unsigned q2 = Xs2[(long)s2 * 64 + l];
        unsigned q3 = Xs2[(long)s3 * 64 + l];
        unsigned q4 = Xs2[(long)s4 * 64 + l];
        unsigned q5 = Xs2[(long)s5 * 64 + l];
        unsigned q6 = Xs2[(long)s6 * 64 + l];
        unsigned q7 = Xs2[(long)s7 * 64 + l];
        a0 += bf2f((ushort)(q0 & 0xffff)); a1 += bf2f((ushort)(q0 >> 16));
        b0 += bf2f((ushort)(q1 & 0xffff)); b1v += bf2f((ushort)(q1 >> 16));
        c0 += bf2f((ushort)(q2 & 0xffff)); c1 += bf2f((ushort)(q2 >> 16));
        d0 += bf2f((ushort)(q3 & 0xffff)); d1 += bf2f((ushort)(q3 >> 16));
        a0 += bf2f((ushort)(q4 & 0xffff)); a1 += bf2f((ushort)(q4 >> 16));
        b0 += bf2f((ushort)(q5 & 0xffff)); b1v += bf2f((ushort)(q5 >> 16));
        c0 += bf2f((ushort)(q6 & 0xffff)); c1 += bf2f((ushort)(q6 >> 16));
        d0 += bf2f((ushort)(q7 & 0xffff)); d1 += bf2f((ushort)(q7 >> 16));
    }
    for (; e < hi; e++) {
        int s = col_idx[e];
        unsigned q = Xs2[(long)s * 64 + l];
        a0 += bf2f((ushort)(q & 0xffff));
        a1 += bf2f((ushort)(q >> 16));
    }
    a0 = (a0 + b0) + (c0 + d0);
    a1 = (a1 + b1v) + (c1 + d1);
    float d = dinv1[i];
    aggX2[(long)i * 64 + l] = (unsigned)f2bf(d * a0) | ((unsigned)f2bf(d * a1) << 16);
}

// ---------------- fused GEMM: abst = tanh(aggX@Wc+bc); S = softmax(abst@fc2_W+b2); zm = dinv2*S ----------------
// Main MFMA (K=128, NC=128) -> tanh tile -> per-wave LDS round-trip (C-layout -> A-layout)
// -> second MFMA (K=128, NC=32) -> intra-quad shuffle softmax -> Sm (fp32), zm (bf16).
__global__ __launch_bounds__(256) void k_gemm_fused(
    const ushort* __restrict__ A, const ushort* __restrict__ Bt,
    const float* __restrict__ bias, const ushort* __restrict__ fc2Wt,
    const float* __restrict__ b2, const float* __restrict__ dinv2,
    float* __restrict__ Sm, ushort* __restrict__ zm, int N)
{
    constexpr int KTOT = FIN, NC = D2;
    constexpr int NT = NC / 16;
    __shared__ ushort Bs[NC * KTOT];       // 32 KB main weight panel
    __shared__ ushort Bs2[KCL * D2];       // 8 KB fc2 weight panel
    __shared__ ushort At[4][16][136];      // 17 KB per-wave abst tiles (row stride 136: bank-spread)
    int t = threadIdx.x;
    constexpr int CPR = KTOT / 8;
    for (int idx = t; idx < NC * CPR; idx += 256) {
        int n = idx / CPR, c = idx % CPR;
        int cs = c ^ (n & 15);
        *(short8*)&Bs[n * KTOT + cs * 8] = *(const short8*)&Bt[(long)n * KTOT + c * 8];
    }
    for (int idx = t; idx < KCL * (D2 / 8); idx += 256) {
        int n = idx / (D2 / 8), c = idx % (D2 / 8);
        int cs = c ^ (n & 15);
        *(short8*)&Bs2[n * D2 + cs * 8] = *(const short8*)&fc2Wt[(long)n * D2 + c * 8];
    }
    __syncthreads();

    int wave = t >> 6, lane = t & 63;
    int quad = lane >> 4, l15 = lane & 15;
    int arow = blockIdx.x * 64 + wave * 16 + l15;
    long aoff_row = (long)min(arow, N - 1) * KTOT;

    floatx4 acc[NT];
#pragma unroll
    for (int tt = 0; tt < NT; tt++) acc[tt] = {0.f, 0.f, 0.f, 0.f};

    for (int k0 = 0; k0 < KTOT; k0 += 32) {
        short8 af = *(const short8*)&A[aoff_row + k0 + quad * 8];
#pragma unroll
        for (int tt = 0; tt < NT; tt++) {
            int n = tt * 16 + l15;
            int cix = ((k0 >> 3) + quad) ^ (n & 15);
            short8 bf = *(const short8*)&Bs[n * KTOT + cix * 8];
            acc[tt] = __builtin_amdgcn_mfma_f32_16x16x32_bf16(af, bf, acc[tt], 0, 0, 0);
        }
    }

    // tanh epilogue -> per-wave LDS tile in row-major [16][128] (A-layout source)
#pragma unroll
    for (int r = 0; r < 4; r++) {
        int row = quad * 4 + r;
#pragma unroll
        for (int tt = 0; tt < NT; tt++) {
            int c = tt * 16 + l15;
            At[wave][row][c] = f2bf(tanhf(acc[tt][r] + bias[c]));
        }
    }
    // second GEMM: S_logits[16x32] = At @ fc2_W   (per-wave private LDS region, no barrier)
    floatx4 accS[2];
    accS[0] = {0.f, 0.f, 0.f, 0.f};
    accS[1] = {0.f, 0.f, 0.f, 0.f};
#pragma unroll
    for (int k0 = 0; k0 < D2; k0 += 32) {
        short8 af = *(const short8*)&At[wave][l15][k0 + quad * 8];
#pragma unroll
        for (int tt = 0; tt < 2; tt++) {
            int n = tt * 16 + l15;
            int cix = ((k0 >> 3) + quad) ^ (n & 15);
            short8 bf = *(const short8*)&Bs2[n * D2 + cix * 8];
            accS[tt] = __builtin_amdgcn_mfma_f32_16x16x32_bf16(af, bf, accS[tt], 0, 0, 0);
        }
    }
    // softmax over 32 cols: row values live in the 16 lanes of this quad, 2 regsets
    float bb0 = b2[l15], bb1 = b2[16 + l15];
    int rbase = blockIdx.x * 64 + wave * 16 + quad * 4;
#pragma unroll
    for (int r = 0; r < 4; r++) {
        int node = rbase + r;
        float v0 = accS[0][r] + bb0;
        float v1 = accS[1][r] + bb1;
        float mx = fmaxf(v0, v1);
#pragma unroll
        for (int mask = 1; mask <= 8; mask <<= 1) mx = fmaxf(mx, __shfl_xor(mx, mask));
        float e0 = __expf(v0 - mx), e1 = __expf(v1 - mx);
        float sum = e0 + e1;
#pragma unroll
        for (int mask = 1; mask <= 8; mask <<= 1) sum += __shfl_xor(sum, mask);
        float inv = 1.0f / sum;
        if (node < N) {
            float sv0 = e0 * inv, sv1 = e1 * inv;
            float d2v = dinv2[node];
            Sm[(long)node * KCL + l15]      = sv0;
            Sm[(long)node * KCL + 16 + l15] = sv1;
            zm[(long)node * KCL + l15]      = f2bf(d2v * sv0);
            zm[(long)node * KCL + 16 + l15] = f2bf(d2v * sv1);
        }
    }
}

// ---------------- fused LS + new_adj: newadj += S^T (S - D2^-1/2 A D2^-1/2 S) ----------------
// 32-lane group per node; LS in registers; 32x32 outer product via shuffles into
// per-lane register accumulators; block merge in LDS; one 1024-atomic flush per block.
__global__ __launch_bounds__(256) void k_LSnew(const float* __restrict__ Sm, const ushort* __restrict__ z,
                                               const int* __restrict__ row_ptr, const ushort* __restrict__ row_idx,
                                               const float* __restrict__ dinv2,
                                               float* __restrict__ newadj, int N) {
    __shared__ float accb[32][33];
    int t = threadIdx.x;
    int g = t >> 5, l = t & 31;
    for (int i = t; i < 32 * 33; i += 256) ((float*)accb)[i] = 0.f;
    float racc[32];
#pragma unroll
    for (int k = 0; k < 32; k++) racc[k] = 0.f;
    __syncthreads();
    for (int i = blockIdx.x * 8 + g; i < N; i += gridDim.x * 8) {
        int lo = row_ptr[i], hi = row_ptr[i + 1];
        float a0 = 0.f, a1 = 0.f, a2 = 0.f, a3 = 0.f;
        int e = lo;
        for (; e + 4 <= hi; e += 4) {
            int c0 = row_idx[e], c1 = row_idx[e + 1], c2 = row_idx[e + 2], c3 = row_idx[e + 3];
            a0 += bf2f(z[(long)c0 * KCL + l]);
            a1 += bf2f(z[(long)c1 * KCL + l]);
            a2 += bf2f(z[(long)c2 * KCL + l]);
            a3 += bf2f(z[(long)c3 * KCL + l]);
        }
        for (; e < hi; e++) a0 += bf2f(z[(long)row_idx[e] * KCL + l]);
        float s = Sm[(long)i * KCL + l];
        float ls = s - dinv2[i] * ((a0 + a1) + (a2 + a3));
#pragma unroll
        for (int k = 0; k < 32; k++) racc[k] += __shfl(s, k, 32) * ls;
    }
#pragma unroll
    for (int k = 0; k < 32; k++) atomicAdd(&accb[k][l], racc[k]);
    __syncthreads();
    for (int i = t; i < 1024; i += 256) atomicAdd(&newadj[i], accb[i >> 5][i & 31]);
}

// ---------------- final: embedding GEMV + pos_penalty ----------------
__global__ __launch_bounds__(256) void k_final(const float* __restrict__ newadj, const float* __restrict__ xsum,
                                               const float* __restrict__ W1, const float* __restrict__ b1,
                                               float* __restrict__ out, int N) {
    __shared__ float xs[FIN];
    __shared__ float nd[32];
    int t = threadIdx.x;
    if (t < FIN) xs[t] = xsum[t];
    if (t < 32) {
        float rs = 0.f;
        for (int l = 0; l < 32; l++) rs += fabsf(newadj[t * 32 + l]);
        nd[t] = newadj[t * 32 + t] / fmaxf(rs, 1e-12f);
    }
    __syncthreads();
    float acc = (float)N * b1[t];
    for (int k = 0; k < FIN; k++) acc += xs[k] * W1[k * D1 + t];
    out[t] = acc * (1.0f / 32.0f);
    if (t == 0) {
        float p = 0.f;
        for (int j = 0; j < 32; j++) {
            float d = nd[j];
            p += 31.0f * d * d + (d - 1.0f) * (d - 1.0f);
        }
        out[256] = p / 1024.0f;
    }
}

extern "C" void kernel_launch(void* const* d_in, const int* in_sizes, int n_in,
                              void* d_out, int out_size, void* d_ws, size_t ws_size,
                              hipStream_t stream) {
    const float* X     = (const float*)d_in[0];
    const int*   edges = (const int*)d_in[1];
    const float* W1    = (const float*)d_in[2];
    const float* b1    = (const float*)d_in[3];
    const float* fc1_W = (const float*)d_in[4];
    const float* fc1_b = (const float*)d_in[5];
    const float* fc2_W = (const float*)d_in[6];
    const float* fc2_b = (const float*)d_in[7];
    float* out = (float*)d_out;

    int N = in_sizes[0] / FIN;
    int E = in_sizes[1] / 2;
    int NBIN = (N + 255) >> 8;

    char* w = (char*)d_ws;
    auto carve = [&](size_t bytes) -> void* {
        void* p = (void*)w;
        w += (bytes + 255) & ~(size_t)255;
        return p;
    };
    ushort* Xs      = (ushort*)carve((size_t)N * FIN * 2);          // bf16 dinv1*X
    ushort* aggX    = (ushort*)carve((size_t)N * FIN * 2);          // bf16 aggregated X
    unsigned* binbuf= (unsigned*)carve((size_t)2 * NBIN * CAP * 4); // dead after P2
    float* Sm       = (float*)carve((size_t)N * KCL * 4);
    ushort* zm      = (ushort*)carve((size_t)N * KCL * 2);          // bf16 z
    float* dinv1    = (float*)carve((size_t)N * 4);
    float* dinv2    = (float*)carve((size_t)N * 4);
    float* vvec     = (float*)carve((size_t)N * 4);
    int* col_ptr    = (int*)carve((size_t)(N + 1) * 4);
    int* row_ptr    = (int*)carve((size_t)(N + 1) * 4);
    ushort* col_idx = (ushort*)carve((size_t)E * 2);
    ushort* row_idx = (ushort*)carve((size_t)E * 2);
    ushort* Wct     = (ushort*)carve((size_t)FIN * D2 * 2);         // [n][k] bf16 composed weight
    ushort* fc2Wt   = (ushort*)carve((size_t)KCL * D2 * 2);         // [n][k] bf16 fc2 weight
    float* bc       = (float*)carve((size_t)D2 * 4);
    float* accum    = (float*)carve((size_t)(1024 + 128 + 512) * 4);
    float* newadj   = accum;
    float* xsum     = accum + 1024;
    int*   gcnt     = (int*)(accum + 1024 + 128);

    hipMemsetAsync(accum, 0, (size_t)(1024 + 128 + 512) * 4, stream);

    k_p1<<<256, 256, 0, stream>>>(edges, E, NBIN, gcnt, binbuf);
    k_p2<<<dim3(NBIN, 2), 256, 0, stream>>>(binbuf, gcnt, N, E, NBIN,
                                            col_ptr, row_ptr, col_idx, row_idx, dinv1, dinv2);
    k_v<<<(N + 255) / 256, 256, 0, stream>>>(row_ptr, row_idx, dinv1, vvec, N);
    k_wc<<<D2 + 1, 128, 0, stream>>>(W1, fc1_W, b1, fc1_b, fc2_W, Wct, bc, fc2Wt);
    k_prep<<<256, 256, 0, stream>>>(X, dinv1, vvec, (unsigned*)Xs, xsum, N);

    k_aggX<<<(N + 3) / 4, 256, 0, stream>>>((const unsigned*)Xs, col_ptr, col_idx, dinv1,
                                            (unsigned*)aggX, N);
    k_gemm_fused<<<(N + 63) / 64, 256, 0, stream>>>(aggX, Wct, bc, fc2Wt, fc2_b, dinv2, Sm, zm, N);
    k_LSnew<<<256, 256, 0, stream>>>(Sm, zm, row_ptr, row_idx, dinv2, newadj, N);
    k_final<<<1, 256, 0, stream>>>(newadj, xsum, W1, b1, out, N);
}

// Round 8
// 298.324 us; speedup vs baseline: 1.0634x; 1.0634x over previous
//
#include <hip/hip_runtime.h>
#include <math.h>

#define FIN 128
#define D1  256
#define D2  128
#define KCL 32
#define CAP 8192          // max edges per 256-node bin (avg ~4082, huge headroom)

typedef __attribute__((ext_vector_type(8))) short short8;
typedef __attribute__((ext_vector_type(4))) float floatx4;

__device__ __forceinline__ ushort f2bf(float f) {
    unsigned u = __float_as_uint(f);
    unsigned r = (u + 0x7fffu + ((u >> 16) & 1u)) >> 16;
    return (ushort)r;
}
__device__ __forceinline__ float bf2f(ushort h) {
    return __uint_as_float(((unsigned)h) << 16);
}

// ---------------- P1: bin-scatter edges, BOTH directions in one edge read ----------------
__global__ __launch_bounds__(256) void k_p1(const int* __restrict__ edges, int E, int NBIN,
                                            int* __restrict__ gcnt, unsigned* __restrict__ binbuf) {
    __shared__ int h[512], base[512], cur[512];
    int t = threadIdx.x;
    h[t] = 0; h[t + 256] = 0;
    __syncthreads();
    int chunk = (E + gridDim.x - 1) / gridDim.x;
    int lo = blockIdx.x * chunk, hi = min(lo + chunk, E);
    for (int e = lo + t; e < hi; e += 256) {
        int r = edges[e], c = edges[E + e];
        atomicAdd(&h[c >> 8], 1);
        atomicAdd(&h[256 + (r >> 8)], 1);
    }
    __syncthreads();
    if (t < NBIN) {
        base[t]       = atomicAdd(&gcnt[t],        h[t]);
        base[256 + t] = atomicAdd(&gcnt[NBIN + t], h[256 + t]);
    }
    cur[t] = 0; cur[t + 256] = 0;
    __syncthreads();
    for (int e = lo + t; e < hi; e += 256) {
        int r = edges[e], c = edges[E + e];
        int b0 = c >> 8;                              // dir0: key dst, store src
        int p0 = base[b0] + atomicAdd(&cur[b0], 1);
        if (p0 < CAP) binbuf[(size_t)b0 * CAP + p0] = (unsigned)r | ((unsigned)(c & 255) << 16);
        int b1 = r >> 8;                              // dir1: key src, store dst
        int p1 = base[256 + b1] + atomicAdd(&cur[256 + b1], 1);
        if (p1 < CAP) binbuf[((size_t)NBIN + b1) * CAP + p1] = (unsigned)c | ((unsigned)(r & 255) << 16);
    }
}

// ---------------- P2: per-bin CSR build + degrees + dinv ----------------
__global__ __launch_bounds__(256) void k_p2(const unsigned* __restrict__ binbuf, const int* __restrict__ gcnt,
                                            int N, int E, int NBIN,
                                            int* __restrict__ col_ptr, int* __restrict__ row_ptr,
                                            ushort* __restrict__ col_idx, ushort* __restrict__ row_idx,
                                            float* __restrict__ dinv1, float* __restrict__ dinv2) {
    int d = blockIdx.y, b = blockIdx.x, t = threadIdx.x;
    __shared__ int sc[256], h[256], hx[256], cur[256];
    sc[t] = (t < NBIN) ? gcnt[d * NBIN + t] : 0;
    __syncthreads();
    for (int st = 1; st < 256; st <<= 1) {
        int u = (t >= st) ? sc[t - st] : 0;
        __syncthreads();
        sc[t] += u;
        __syncthreads();
    }
    int cnt_b = gcnt[d * NBIN + b];
    int binbase = sc[b] - cnt_b;
    h[t] = 0;
    __syncthreads();
    const unsigned* bb = binbuf + ((size_t)d * NBIN + b) * CAP;
    int m = min(cnt_b, CAP);
    for (int i = t; i < m; i += 256) atomicAdd(&h[bb[i] >> 16], 1);
    __syncthreads();
    int hv = h[t];
    hx[t] = hv;
    __syncthreads();
    for (int st = 1; st < 256; st <<= 1) {
        int u = (t >= st) ? hx[t - st] : 0;
        __syncthreads();
        hx[t] += u;
        __syncthreads();
    }
    int excl = hx[t] - hv;
    int node = b * 256 + t;
    if (node < N) {
        if (d == 0) {
            dinv1[node] = rsqrtf((float)hv + 1.0f);
            col_ptr[node] = binbase + excl;
            if (node == N - 1) col_ptr[N] = E;
        } else {
            dinv2[node] = hv ? rsqrtf((float)hv) : 0.0f;
            row_ptr[node] = binbase + excl;
            if (node == N - 1) row_ptr[N] = E;
        }
    }
    hx[t] = excl;
    cur[t] = 0;
    __syncthreads();
    ushort* oidx = d ? row_idx : col_idx;
    for (int i = t; i < m; i += 256) {
        unsigned p = bb[i];
        int nl = p >> 16;
        int rk = atomicAdd(&cur[nl], 1);
        oidx[binbase + hx[nl] + rk] = (ushort)(p & 0xffff);
    }
}

// ---------------- v_j = dinv1[j]*(dinv1[j] + sum_{i in out(j)} dinv1[i]) ----------------
__global__ void k_v(const int* __restrict__ row_ptr, const ushort* __restrict__ row_idx,
                    const float* __restrict__ dinv1, float* __restrict__ v, int N) {
    int j = blockIdx.x * blockDim.x + threadIdx.x;
    if (j >= N) return;
    int lo = row_ptr[j], hi = row_ptr[j + 1];
    float s0 = dinv1[j], s1 = 0.f, s2 = 0.f, s3 = 0.f;
    int e = lo;
    for (; e + 4 <= hi; e += 4) {
        int i0 = row_idx[e], i1 = row_idx[e + 1], i2 = row_idx[e + 2], i3 = row_idx[e + 3];
        s0 += dinv1[i0]; s1 += dinv1[i1]; s2 += dinv1[i2]; s3 += dinv1[i3];
    }
    for (; e < hi; e++) s0 += dinv1[row_idx[e]];
    v[j] = dinv1[j] * ((s0 + s1) + (s2 + s3));
}

// ---------------- fused: Xs = bf16(dinv1*X), xsum[c] += v[j]*X[j][c] ----------------
__global__ __launch_bounds__(256) void k_prep(const float* __restrict__ X, const float* __restrict__ dinv1,
                                              const float* __restrict__ vvec,
                                              unsigned* __restrict__ Xs2, float* __restrict__ xsum, int N) {
    int t = threadIdx.x;
    int cp = t & 63;        // col-pair (cols 2cp, 2cp+1)
    int rg = t >> 6;        // row group 0..3
    float s0 = 0.f, s1 = 0.f;
    for (int j0 = blockIdx.x * 4; j0 < N; j0 += gridDim.x * 4) {
        int j = j0 + rg;
        if (j < N) {
            float2 x = ((const float2*)X)[(long)j * 64 + cp];
            float d = dinv1[j];
            Xs2[(long)j * 64 + cp] = (unsigned)f2bf(d * x.x) | ((unsigned)f2bf(d * x.y) << 16);
            float v = vvec[j];
            s0 += v * x.x;
            s1 += v * x.y;
        }
    }
    __shared__ float red[256][2];
    red[t][0] = s0; red[t][1] = s1;
    __syncthreads();
    if (rg == 0) {
        float r0 = red[cp][0] + red[64 + cp][0] + red[128 + cp][0] + red[192 + cp][0];
        float r1 = red[cp][1] + red[64 + cp][1] + red[128 + cp][1] + red[192 + cp][1];
        atomicAdd(&xsum[2 * cp], r0);
        atomicAdd(&xsum[2 * cp + 1], r1);
    }
}

// ---------------- Wc = W1 @ fc1_W (fp32) -> bf16 transposed; bc; fc2_W -> bf16 transposed ----------------
__global__ __launch_bounds__(128) void k_wc(const float* __restrict__ W1, const float* __restrict__ fc1W,
                                            const float* __restrict__ b1, const float* __restrict__ fc1b,
                                            const float* __restrict__ fc2W,
                                            ushort* __restrict__ Wct, float* __restrict__ bc,
                                            ushort* __restrict__ fc2Wt) {
    int t = threadIdx.x;
    if (blockIdx.x == D2) {   // extra block: transpose fc2_W [128][32] -> [32][128] bf16
        for (int idx = t; idx < D2 * KCL; idx += 128) {
            int k = idx >> 5, n = idx & 31;
            fc2Wt[n * D2 + k] = f2bf(fc2W[idx]);
        }
        return;
    }
    int n = blockIdx.x, k = t;
    __shared__ float fcol[256];
    fcol[k] = fc1W[k * 128 + n];
    fcol[k + 128] = fc1W[(k + 128) * 128 + n];
    __syncthreads();
    float acc = 0.f;
    for (int m = 0; m < 256; m++) acc += W1[k * 256 + m] * fcol[m];
    Wct[n * 128 + k] = f2bf(acc);
    if (k == 0) {
        float a = fc1b[n];
        for (int m = 0; m < 256; m++) a += b1[m] * fcol[m];
        bc[n] = a;
    }
}

// ---------------- aggX[i] = bf16( dinv1[i] * sum_{j in in(i)+self} Xs[j] ) ----------------
__global__ __launch_bounds__(256) void k_aggX(const unsigned* __restrict__ Xs2,
                                              const int* __restrict__ col_ptr, const ushort* __restrict__ col_idx,
                                              const float* __restrict__ dinv1,
                                              unsigned* __restrict__ aggX2, int N) {
    int wv = threadIdx.x >> 6, l = threadIdx.x & 63;
    int i = blockIdx.x * 4 + wv;
    if (i >= N) return;
    int lo = col_ptr[i], hi = col_ptr[i + 1];
    unsigned p0 = Xs2[(long)i * 64 + l];
    float a0 = bf2f((ushort)(p0 & 0xffff));
    float a1 = bf2f((ushort)(p0 >> 16));
    float b0 = 0.f, b1v = 0.f, c0 = 0.f, c1 = 0.f, d0 = 0.f, d1 = 0.f;
    int e = lo;
    for (; e + 8 <= hi; e += 8) {
        int s0 = col_idx[e + 0], s1 = col_idx[e + 1], s2 = col_idx[e + 2], s3 = col_idx[e + 3];
        int s4 = col_idx[e + 4], s5 = col_idx[e + 5], s6 = col_idx[e + 6], s7 = col_idx[e + 7];
        unsigned q0 = Xs2[(long)s0 * 64 + l];
        unsigned q1 = Xs2[(long)s1 * 64 + l];
        unsigned q2 = Xs2[(long)s2 * 64 + l];
        unsigned q3 = Xs2[(long)s3 * 64 + l];
        unsigned q4 = Xs2[(long)s4 * 64 + l];
        unsigned q5 = Xs2[(long)s5 * 64 + l];
        unsigned q6 = Xs2[(long)s6 * 64 + l];
        unsigned q7 = Xs2[(long)s7 * 64 + l];
        a0 += bf2f((ushort)(q0 & 0xffff)); a1 += bf2f((ushort)(q0 >> 16));
        b0 += bf2f((ushort)(q1 & 0xffff)); b1v += bf2f((ushort)(q1 >> 16));
        c0 += bf2f((ushort)(q2 & 0xffff)); c1 += bf2f((ushort)(q2 >> 16));
        d0 += bf2f((ushort)(q3 & 0xffff)); d1 += bf2f((ushort)(q3 >> 16));
        a0 += bf2f((ushort)(q4 & 0xffff)); a1 += bf2f((ushort)(q4 >> 16));
        b0 += bf2f((ushort)(q5 & 0xffff)); b1v += bf2f((ushort)(q5 >> 16));
        c0 += bf2f((ushort)(q6 & 0xffff)); c1 += bf2f((ushort)(q6 >> 16));
        d0 += bf2f((ushort)(q7 & 0xffff)); d1 += bf2f((ushort)(q7 >> 16));
    }
    for (; e < hi; e++) {
        int s = col_idx[e];
        unsigned q = Xs2[(long)s * 64 + l];
        a0 += bf2f((ushort)(q & 0xffff));
        a1 += bf2f((ushort)(q >> 16));
    }
    a0 = (a0 + b0) + (c0 + d0);
    a1 = (a1 + b1v) + (c1 + d1);
    float d = dinv1[i];
    aggX2[(long)i * 64 + l] = (unsigned)f2bf(d * a0) | ((unsigned)f2bf(d * a1) << 16);
}

// ---------------- fused GEMM: abst = tanh(aggX@Wc+bc); S = softmax(abst@fc2_W+b2); zm = dinv2*S ----------------
__global__ __launch_bounds__(256) void k_gemm_fused(
    const ushort* __restrict__ A, const ushort* __restrict__ Bt,
    const float* __restrict__ bias, const ushort* __restrict__ fc2Wt,
    const float* __restrict__ b2, const float* __restrict__ dinv2,
    ushort* __restrict__ Sbf, ushort* __restrict__ zm, int N)
{
    constexpr int KTOT = FIN, NC = D2;
    constexpr int NT = NC / 16;
    __shared__ ushort Bs[NC * KTOT];       // 32 KB main weight panel
    __shared__ ushort Bs2[KCL * D2];       // 8 KB fc2 weight panel
    __shared__ ushort At[4][16][136];      // 17 KB per-wave abst tiles (row stride 136: bank-spread)
    int t = threadIdx.x;
    constexpr int CPR = KTOT / 8;
    for (int idx = t; idx < NC * CPR; idx += 256) {
        int n = idx / CPR, c = idx % CPR;
        int cs = c ^ (n & 15);
        *(short8*)&Bs[n * KTOT + cs * 8] = *(const short8*)&Bt[(long)n * KTOT + c * 8];
    }
    for (int idx = t; idx < KCL * (D2 / 8); idx += 256) {
        int n = idx / (D2 / 8), c = idx % (D2 / 8);
        int cs = c ^ (n & 15);
        *(short8*)&Bs2[n * D2 + cs * 8] = *(const short8*)&fc2Wt[(long)n * D2 + c * 8];
    }
    __syncthreads();

    int wave = t >> 6, lane = t & 63;
    int quad = lane >> 4, l15 = lane & 15;
    int arow = blockIdx.x * 64 + wave * 16 + l15;
    long aoff_row = (long)min(arow, N - 1) * KTOT;

    floatx4 acc[NT];
#pragma unroll
    for (int tt = 0; tt < NT; tt++) acc[tt] = {0.f, 0.f, 0.f, 0.f};

    for (int k0 = 0; k0 < KTOT; k0 += 32) {
        short8 af = *(const short8*)&A[aoff_row + k0 + quad * 8];
#pragma unroll
        for (int tt = 0; tt < NT; tt++) {
            int n = tt * 16 + l15;
            int cix = ((k0 >> 3) + quad) ^ (n & 15);
            short8 bf = *(const short8*)&Bs[n * KTOT + cix * 8];
            acc[tt] = __builtin_amdgcn_mfma_f32_16x16x32_bf16(af, bf, acc[tt], 0, 0, 0);
        }
    }

    // tanh epilogue -> per-wave LDS tile in row-major [16][128] (A-layout source)
#pragma unroll
    for (int r = 0; r < 4; r++) {
        int row = quad * 4 + r;
#pragma unroll
        for (int tt = 0; tt < NT; tt++) {
            int c = tt * 16 + l15;
            At[wave][row][c] = f2bf(tanhf(acc[tt][r] + bias[c]));
        }
    }
    // second GEMM: S_logits[16x32] = At @ fc2_W   (per-wave private LDS region, no barrier)
    floatx4 accS[2];
    accS[0] = {0.f, 0.f, 0.f, 0.f};
    accS[1] = {0.f, 0.f, 0.f, 0.f};
#pragma unroll
    for (int k0 = 0; k0 < D2; k0 += 32) {
        short8 af = *(const short8*)&At[wave][l15][k0 + quad * 8];
#pragma unroll
        for (int tt = 0; tt < 2; tt++) {
            int n = tt * 16 + l15;
            int cix = ((k0 >> 3) + quad) ^ (n & 15);
            short8 bf = *(const short8*)&Bs2[n * D2 + cix * 8];
            accS[tt] = __builtin_amdgcn_mfma_f32_16x16x32_bf16(af, bf, accS[tt], 0, 0, 0);
        }
    }
    // softmax over 32 cols: row values live in the 16 lanes of this quad, 2 regsets
    float bb0 = b2[l15], bb1 = b2[16 + l15];
    int rbase = blockIdx.x * 64 + wave * 16 + quad * 4;
#pragma unroll
    for (int r = 0; r < 4; r++) {
        int node = rbase + r;
        float v0 = accS[0][r] + bb0;
        float v1 = accS[1][r] + bb1;
        float mx = fmaxf(v0, v1);
#pragma unroll
        for (int mask = 1; mask <= 8; mask <<= 1) mx = fmaxf(mx, __shfl_xor(mx, mask));
        float e0 = __expf(v0 - mx), e1 = __expf(v1 - mx);
        float sum = e0 + e1;
#pragma unroll
        for (int mask = 1; mask <= 8; mask <<= 1) sum += __shfl_xor(sum, mask);
        float inv = 1.0f / sum;
        if (node < N) {
            float sv0 = e0 * inv, sv1 = e1 * inv;
            float d2v = dinv2[node];
            Sbf[(long)node * KCL + l15]      = f2bf(sv0);
            Sbf[(long)node * KCL + 16 + l15] = f2bf(sv1);
            zm[(long)node * KCL + l15]       = f2bf(d2v * sv0);
            zm[(long)node * KCL + 16 + l15]  = f2bf(d2v * sv1);
        }
    }
}

// ---------------- fused LS + new_adj: newadj += S^T (S - D2^-1/2 A D2^-1/2 S) ----------------
// 32-lane group per node; LS in registers; outer product via shuffles into per-lane
// register accumulators; block merge in LDS; one 1024-atomic flush per block.
// grid=1024: 4 blocks/CU (16 waves/CU) — the R7 92us regression was 1 block/CU starvation.
__global__ __launch_bounds__(256) void k_LSnew(const ushort* __restrict__ Sbf, const ushort* __restrict__ z,
                                               const int* __restrict__ row_ptr, const ushort* __restrict__ row_idx,
                                               const float* __restrict__ dinv2,
                                               float* __restrict__ newadj, int N) {
    __shared__ float accb[32][33];
    int t = threadIdx.x;
    int g = t >> 5, l = t & 31;
    for (int i = t; i < 32 * 33; i += 256) ((float*)accb)[i] = 0.f;
    float racc[32];
#pragma unroll
    for (int k = 0; k < 32; k++) racc[k] = 0.f;
    __syncthreads();
    for (int i = blockIdx.x * 8 + g; i < N; i += gridDim.x * 8) {
        int lo = row_ptr[i], hi = row_ptr[i + 1];
        float a0 = 0.f, a1 = 0.f, a2 = 0.f, a3 = 0.f;
        int e = lo;
        for (; e + 4 <= hi; e += 4) {
            int c0 = row_idx[e], c1 = row_idx[e + 1], c2 = row_idx[e + 2], c3 = row_idx[e + 3];
            a0 += bf2f(z[(long)c0 * KCL + l]);
            a1 += bf2f(z[(long)c1 * KCL + l]);
            a2 += bf2f(z[(long)c2 * KCL + l]);
            a3 += bf2f(z[(long)c3 * KCL + l]);
        }
        for (; e < hi; e++) a0 += bf2f(z[(long)row_idx[e] * KCL + l]);
        float s = bf2f(Sbf[(long)i * KCL + l]);
        float ls = s - dinv2[i] * ((a0 + a1) + (a2 + a3));
#pragma unroll
        for (int k = 0; k < 32; k++) racc[k] += __shfl(s, k, 32) * ls;
    }
#pragma unroll
    for (int k = 0; k < 32; k++) atomicAdd(&accb[k][l], racc[k]);
    __syncthreads();
    for (int i = t; i < 1024; i += 256) atomicAdd(&newadj[i], accb[i >> 5][i & 31]);
}

// ---------------- final: embedding GEMV + pos_penalty ----------------
__global__ __launch_bounds__(256) void k_final(const float* __restrict__ newadj, const float* __restrict__ xsum,
                                               const float* __restrict__ W1, const float* __restrict__ b1,
                                               float* __restrict__ out, int N) {
    __shared__ float xs[FIN];
    __shared__ float nd[32];
    int t = threadIdx.x;
    if (t < FIN) xs[t] = xsum[t];
    if (t < 32) {
        float rs = 0.f;
        for (int l = 0; l < 32; l++) rs += fabsf(newadj[t * 32 + l]);
        nd[t] = newadj[t * 32 + t] / fmaxf(rs, 1e-12f);
    }
    __syncthreads();
    float acc = (float)N * b1[t];
    for (int k = 0; k < FIN; k++) acc += xs[k] * W1[k * D1 + t];
    out[t] = acc * (1.0f / 32.0f);
    if (t == 0) {
        float p = 0.f;
        for (int j = 0; j < 32; j++) {
            float d = nd[j];
            p += 31.0f * d * d + (d - 1.0f) * (d - 1.0f);
        }
        out[256] = p / 1024.0f;
    }
}

extern "C" void kernel_launch(void* const* d_in, const int* in_sizes, int n_in,
                              void* d_out, int out_size, void* d_ws, size_t ws_size,
                              hipStream_t stream) {
    const float* X     = (const float*)d_in[0];
    const int*   edges = (const int*)d_in[1];
    const float* W1    = (const float*)d_in[2];
    const float* b1    = (const float*)d_in[3];
    const float* fc1_W = (const float*)d_in[4];
    const float* fc1_b = (const float*)d_in[5];
    const float* fc2_W = (const float*)d_in[6];
    const float* fc2_b = (const float*)d_in[7];
    float* out = (float*)d_out;

    int N = in_sizes[0] / FIN;
    int E = in_sizes[1] / 2;
    int NBIN = (N + 255) >> 8;

    char* w = (char*)d_ws;
    auto carve = [&](size_t bytes) -> void* {
        void* p = (void*)w;
        w += (bytes + 255) & ~(size_t)255;
        return p;
    };
    ushort* Xs      = (ushort*)carve((size_t)N * FIN * 2);          // bf16 dinv1*X
    ushort* aggX    = (ushort*)carve((size_t)N * FIN * 2);          // bf16 aggregated X
    unsigned* binbuf= (unsigned*)carve((size_t)2 * NBIN * CAP * 4); // dead after P2
    ushort* Sbf     = (ushort*)carve((size_t)N * KCL * 2);          // bf16 S
    ushort* zm      = (ushort*)carve((size_t)N * KCL * 2);          // bf16 z
    float* dinv1    = (float*)carve((size_t)N * 4);
    float* dinv2    = (float*)carve((size_t)N * 4);
    float* vvec     = (float*)carve((size_t)N * 4);
    int* col_ptr    = (int*)carve((size_t)(N + 1) * 4);
    int* row_ptr    = (int*)carve((size_t)(N + 1) * 4);
    ushort* col_idx = (ushort*)carve((size_t)E * 2);
    ushort* row_idx = (ushort*)carve((size_t)E * 2);
    ushort* Wct     = (ushort*)carve((size_t)FIN * D2 * 2);         // [n][k] bf16 composed weight
    ushort* fc2Wt   = (ushort*)carve((size_t)KCL * D2 * 2);         // [n][k] bf16 fc2 weight
    float* bc       = (float*)carve((size_t)D2 * 4);
    float* accum    = (float*)carve((size_t)(1024 + 128 + 512) * 4);
    float* newadj   = accum;
    float* xsum     = accum + 1024;
    int*   gcnt     = (int*)(accum + 1024 + 128);

    hipMemsetAsync(accum, 0, (size_t)(1024 + 128 + 512) * 4, stream);

    k_p1<<<256, 256, 0, stream>>>(edges, E, NBIN, gcnt, binbuf);
    k_p2<<<dim3(NBIN, 2), 256, 0, stream>>>(binbuf, gcnt, N, E, NBIN,
                                            col_ptr, row_ptr, col_idx, row_idx, dinv1, dinv2);
    k_v<<<(N + 255) / 256, 256, 0, stream>>>(row_ptr, row_idx, dinv1, vvec, N);
    k_wc<<<D2 + 1, 128, 0, stream>>>(W1, fc1_W, b1, fc1_b, fc2_W, Wct, bc, fc2Wt);
    k_prep<<<256, 256, 0, stream>>>(X, dinv1, vvec, (unsigned*)Xs, xsum, N);

    k_aggX<<<(N + 3) / 4, 256, 0, stream>>>((const unsigned*)Xs, col_ptr, col_idx, dinv1,
                                            (unsigned*)aggX, N);
    k_gemm_fused<<<(N + 63) / 64, 256, 0, stream>>>(aggX, Wct, bc, fc2Wt, fc2_b, dinv2, Sbf, zm, N);
    k_LSnew<<<1024, 256, 0, stream>>>(Sbf, zm, row_ptr, row_idx, dinv2, newadj, N);
    k_final<<<1, 256, 0, stream>>>(newadj, xsum, W1, b1, out, N);
}